// Round 6
// baseline (12936.694 us; speedup 1.0000x reference)
//
#include <hip/hip_runtime.h>
#include <math.h>

// Problem constants (N=2, C=64, H=96, W=96, PATCH=3)
static constexpr int NITEM = 2;
static constexpr int C = 64;
static constexpr int W = 96;
static constexpr int H = 96;
static constexpr int HW = H * W;        // 9216
static constexpr int HP = 94;           // H - 3 + 1
static constexpr int NP = HP * HP;      // 8836

// Work units: per (n, dy) split the valid yi-range into PL-row pieces.
static constexpr int PL = 8;
static constexpr int UNITS_PER_N = 1188;
static constexpr int NBLOCKS = 1024;    // 4 blocks/CU x 256 CUs

// Order-preserving fp32 -> uint32 (v1 > v2  <=>  key(v1) > key(v2))
__device__ __forceinline__ unsigned int fkey(float v) {
    unsigned int u = __float_as_uint(v);
    return (u & 0x80000000u) ? ~u : (u | 0x80000000u);
}

// ---------------- Kernel 1: normalize + per-row panel repack ----------------
// fiP/frP: per-row panel images [n][row][c2][x] float2 (linear 24576B/row -> DMA-able)
__global__ __launch_bounds__(256) void normalize_kernel(
    const float* __restrict__ f1, const float* __restrict__ f2,
    float2* __restrict__ fiP, float2* __restrict__ frP, float* __restrict__ ssn)
{
    int t = blockIdx.x * 256 + threadIdx.x;
    const int perTensor = NITEM * HW;
    if (t >= 2 * perTensor) return;
    int which = t / perTensor;
    int p = t - which * perTensor;
    int n = p / HW;
    int pix = p - n * HW;
    const float* src = (which ? f2 : f1) + (size_t)n * C * HW + pix;
    float s = 0.f;
    #pragma unroll
    for (int c = 0; c < C; c++) {
        float v = src[c * HW];
        s = fmaf(v, v, s);
    }
    float norm = sqrtf(s);
    float scale = 1.0f / fmaxf(norm, 1e-12f);
    int y = pix / W, x = pix - y * W;
    float2* base = (which ? frP : fiP) + ((size_t)n * H + y) * (32 * W) + x;
    #pragma unroll
    for (int c2 = 0; c2 < 32; c2++)
        base[c2 * W] = make_float2(src[(2 * c2) * HW] * scale,
                                   src[(2 * c2 + 1) * HW] * scale);
    if (which) ssn[p] = s * scale * scale;
}

// ---------------- Kernel 2: ref patch inverse norms ----------------
__global__ __launch_bounds__(256) void refnorm_kernel(
    const float* __restrict__ ssn, float* __restrict__ invn)
{
    int t = blockIdx.x * 256 + threadIdx.x;
    if (t >= NITEM * NP) return;
    int n = t / NP;
    int r = t - n * NP;
    int yr = r / HP, xr = r - yr * HP;
    const float* s = ssn + n * HW;
    float acc = 0.f;
    #pragma unroll
    for (int dy = 0; dy < 3; dy++)
        #pragma unroll
        for (int dx = 0; dx < 3; dx++)
            acc += s[(yr + dy) * W + (xr + dx)];
    invn[t] = 1.0f / (sqrtf(acc) + 1e-5f);
}

// ---- async quarter staging: 12288 B (A 6144 | B 6144) -> one LDS slot ----
// 12 chunks of 1024 B; wave wv stages chunks 3wv..3wv+2 (waves 0-1 -> A, 2-3 -> B).
__device__ __forceinline__ void stage_quarter(const char* aQ, const char* bQ,
                                              char* slot, int wv, int lane)
{
#if defined(__has_builtin) && __has_builtin(__builtin_amdgcn_global_load_lds)
    #pragma unroll
    for (int c = 0; c < 3; ++c) {
        const int off = (wv * 3 + c) << 10;
        const char* g = ((off < 6144) ? (aQ + off) : (bQ + (off - 6144))) + lane * 16;
        __builtin_amdgcn_global_load_lds(
            (const __attribute__((address_space(1))) unsigned int*)(const void*)g,
            (__attribute__((address_space(3))) unsigned int*)(void*)(slot + off),
            16, 0, 0);
    }
#else
    #pragma unroll
    for (int c = 0; c < 3; ++c) {
        const int off = ((wv * 3 + c) << 10) + lane * 16;
        const char* g = (off < 6144) ? (aQ + off) : (bQ + (off - 6144));
        *(float4*)(slot + off) = *(const float4*)g;
    }
#endif
}

// ---------------- Kernel 3: fused row-pair GEMM + register diagonal taps + argmax ----
// Same math as the passing R5 kernel (bit-identical association/tie-break); the
// K-panels are now staged as four 8-c2 quarters through two ping-pong LDS slots:
//   per step: 4 x { barrier (implicit vmcnt drain) -> issue next-quarter DMA
//                   -> GEMM 8 kp from slot[p&1] },
// with taps/finalize for step y folded into phase 0 of step y+1 (overlaps DMA).
// LDS 26.4 KB + VGPR<=128 -> 4 blocks/CU (16 waves) vs R5's 3 (12 waves).
__global__ __launch_bounds__(256, 4) void corr_fused_kernel(
    const float2* __restrict__ fiP, const float2* __restrict__ frP,
    const float* __restrict__ invn, unsigned long long* __restrict__ best,
    unsigned int* __restrict__ tick)
{
    __shared__ struct {
        float2 slab[2][2][8][96];   // 24576 B: [slot][op A/B][kp8][x]
        float  sh[3][2][100];       //  2400 B: halo rows for wave-boundary groups
        int    sp;
    } sm;                           // ~26.4 KB

    const int t = threadIdx.x;
    const int tu = t >> 4, tv = t & 15;     // 16x16 grid of 6x6 fragments
    const int lane = t & 63;
    const int quad = tu & 3;                // row-subgroup within wave
    const int wv = t >> 6;
    const int u0 = 6 * tu, v0 = 6 * tv;
    const unsigned long long gmask = 0xFFFFull << (lane & 48);

    const int n = blockIdx.x & 1;           // 512 blocks per item, XCD-interleaved

    const float2* fiPn = fiP + (size_t)n * H * (32 * W);
    const float2* frPn = frP + (size_t)n * H * (32 * W);
    const float* inv = invn + (size_t)n * NP;
    unsigned long long* bn = best + (size_t)n * NP;

    float pA[6][6], pB[6][6];
    float acc[6][6];
    int dy = 0, ya = 0;

    // ---- taps + y-rotation + finalize for step Y (reads acc, halo; updates pend) ----
    auto do_taps = [&](int Y) {
        const bool doFin = (Y >= ya + 2);
        const bool doA = (Y > ya);
        const int yi = Y - 2;
        const int yr = yi + dy;

        // neighbor exchange (uniform shfls; select after)
        float c6[6], c7[6];
        #pragma unroll
        for (int i = 0; i < 6; ++i) {
            c6[i] = __shfl_down(acc[i][0], 1);   // col u0+i, v0+6
            c7[i] = __shfl_down(acc[i][1], 1);   // col u0+i, v0+7
        }
        float e6[8], e7[8];
        #pragma unroll
        for (int jj = 0; jj < 6; ++jj) {
            e6[jj] = __shfl_down(acc[0][jj], 16);  // row u0+6
            e7[jj] = __shfl_down(acc[1][jj], 16);  // row u0+7
        }
        e6[6] = __shfl_down(acc[0][0], 17);
        e6[7] = __shfl_down(acc[0][1], 17);
        e7[6] = __shfl_down(acc[1][0], 17);
        e7[7] = __shfl_down(acc[1][1], 17);
        if (quad == 3) {
            if (tu < 15) {
                const int g = tu >> 2;
                #pragma unroll
                for (int jj = 0; jj < 8; ++jj) {
                    e6[jj] = sm.sh[g][0][v0 + jj];
                    e7[jj] = sm.sh[g][1][v0 + jj];
                }
            } else {
                #pragma unroll
                for (int jj = 0; jj < 8; ++jj) { e6[jj] = 0.f; e7[jj] = 0.f; }
            }
        }

        float ivr[6];
        if (doFin) {
            const float* ivp = inv + (size_t)yr * HP;
            #pragma unroll
            for (int jj = 0; jj < 6; ++jj) {
                int xr = v0 + jj;
                ivr[jj] = ivp[xr > 93 ? 93 : xr];   // clamp; garbage masked later
            }
        }

        #pragma unroll
        for (int i = 0; i < 6; ++i) {
            float bv = -INFINITY; int bxr = 0;
            #pragma unroll
            for (int jj = 0; jj < 6; ++jj) {
                const int i1 = (i + 1 <= 5) ? i + 1 : 0;
                const int j1 = (jj + 1 <= 5) ? jj + 1 : 0;
                const int i2 = (i + 2 <= 5) ? i + 2 : 0;
                const int j2 = (jj + 2 <= 5) ? jj + 2 : 0;
                float E0 = acc[i][jj];
                float E1 = (i + 1 <= 5)
                         ? ((jj + 1 <= 5) ? acc[i1][j1] : c6[i1])
                         : e6[jj + 1];
                float E2 = (i + 2 <= 5)
                         ? ((jj + 2 <= 5) ? acc[i2][j2]
                                          : ((jj + 2 == 6) ? c6[i2] : c7[i2]))
                         : ((i + 2 == 6) ? e6[jj + 2] : e7[jj + 2]);
                float bx = (E0 + E1) + E2;           // (g0+g1)+g2, as pass2
                if (doFin) {
                    float v = (pA[i][jj] + bx) * ivr[jj];  // ((B0+B1)+B2)*inv
                    int xr = v0 + jj;
                    if (xr < HP && (u0 + i) < HP && v > bv) { bv = v; bxr = xr; }
                }
                if (doA) pA[i][jj] = pB[i][jj] + bx;
                pB[i][jj] = bx;
            }
            if (doFin) {
                float mx = bv;
                #pragma unroll
                for (int m = 1; m < 16; m <<= 1)
                    mx = fmaxf(mx, __shfl_xor(mx, m));   // 16-lane xr-group max
                unsigned long long ball = __ballot(bv == mx) & gmask;
                int srcl = __ffsll(ball) - 1;            // lowest lane = min xr
                int wxr = __shfl(bxr, srcl);
                if (tv == 0 && (u0 + i) < HP) {
                    unsigned long long key =
                        ((unsigned long long)fkey(mx) << 32)
                      | (unsigned int)(~(unsigned int)(yr * HP + wxr));
                    const size_t off = (size_t)yi * HP + (u0 + i);
                    if (key > bn[off]) atomicMax(&bn[off], key);  // monotone: stale-skip safe
                }
            }
        }
    };

    // ---- 8-kp GEMM sub-phase from one slot ----
    auto gemm8 = [&](int s) {
        #pragma unroll
        for (int k = 0; k < 8; ++k) {
            const float4* ap = (const float4*)&sm.slab[s][0][k][u0];
            const float4* bp = (const float4*)&sm.slab[s][1][k][v0];
            float4 a01 = ap[0], a23 = ap[1], a45 = ap[2];
            float4 b01 = bp[0], b23 = bp[1], b45 = bp[2];
            float ae[6] = {a01.x, a01.z, a23.x, a23.z, a45.x, a45.z};
            float ao[6] = {a01.y, a01.w, a23.y, a23.w, a45.y, a45.w};
            float be[6] = {b01.x, b01.z, b23.x, b23.z, b45.x, b45.z};
            float bo[6] = {b01.y, b01.w, b23.y, b23.w, b45.y, b45.w};
            #pragma unroll
            for (int i = 0; i < 6; ++i)
                #pragma unroll
                for (int jj = 0; jj < 6; ++jj) {
                    acc[i][jj] = fmaf(ae[i], be[jj], acc[i][jj]);  // even ch then
                    acc[i][jj] = fmaf(ao[i], bo[jj], acc[i][jj]);  // odd: asc-c chain
                }
        }
    };

    auto do_stage = [&](int ty, int tp) {
        stage_quarter((const char*)(fiPn + (size_t)ty * (32 * W)) + tp * 6144,
                      (const char*)(frPn + (size_t)(ty + dy) * (32 * W)) + tp * 6144,
                      (char*)&sm.slab[tp & 1][0][0][0], wv, lane);
    };

    for (;;) {
        if (t == 0) sm.sp = (int)atomicAdd(&tick[n * 16], 1u);
        __syncthreads();
        const int uj = sm.sp;               // unit index within item
        if (uj >= UNITS_PER_N) break;

        // ---- decode unit -> (dy, ya, nb), center-out dy order ----
        int nb = 0;
        {
            int r = uj;
            for (int s = 0; s < 187; ++s) {
                int ady = (s + 1) >> 1;          // 0,1,1,2,2,...,93,93
                int nyi = 94 - ady;
                int q = (nyi + PL - 1) / PL;
                if (r < q) {
                    dy = (s & 1) ? -ady : ady;
                    ya = (dy < 0 ? -dy : 0) + r * PL;
                    nb = nyi - r * PL; if (nb > PL) nb = PL;
                    break;
                }
                r -= q;
            }
        }
        const int yb = ya + nb;             // finalize yi in [ya, yb); GEMM y: ya..yb+1

        do_stage(ya, 0);                    // prologue: quarter 0 of first row-pair

        for (int y = ya; y <= yb + 2; ++y) {
            __syncthreads();                // ph0 barrier: drains slot0 DMA
            if (y <= yb + 1) {
                do_stage(y, 1);                       // -> slot1
                if (y > ya) do_taps(y - 1);           // prev step's taps (reads old acc)
                #pragma unroll
                for (int i = 0; i < 6; ++i)
                    #pragma unroll
                    for (int jj = 0; jj < 6; ++jj) acc[i][jj] = 0.f;
                gemm8(0);                             // kp 0-7

                __syncthreads();                      // drains slot1 DMA
                do_stage(y, 2);                       // -> slot0
                gemm8(1);                             // kp 8-15

                __syncthreads();                      // drains slot0 DMA
                do_stage(y, 3);                       // -> slot1
                gemm8(0);                             // kp 16-23

                __syncthreads();                      // drains slot1 DMA
                if (y < yb + 1) do_stage(y + 1, 0);   // -> slot0 (next row-pair)
                gemm8(1);                             // kp 24-31

                // publish halo rows 0,1 for wave-boundary consumers (tu in {3,7,11})
                if (quad == 0 && tu >= 4) {
                    const int g = (tu >> 2) - 1;
                    #pragma unroll
                    for (int jj = 0; jj < 6; ++jj) {
                        sm.sh[g][0][v0 + jj] = acc[0][jj];
                        sm.sh[g][1][v0 + jj] = acc[1][jj];
                    }
                }
            } else {
                do_taps(y - 1);             // final taps (no GEMM this iteration)
            }
        }
    }
}

// ---------------- Kernel 4: expand to 9 shifted copies, channel-interleaved ----------------
__global__ __launch_bounds__(256) void expand_best_kernel(
    const unsigned long long* __restrict__ best, float* __restrict__ out)
{
    int t = blockIdx.x * 256 + threadIdx.x;
    const int total = NITEM * 18 * HW;
    if (t >= total) return;
    int x = t % W;
    int y = (t / W) % H;
    int chn = (t / HW) % 18;
    int n = t / (18 * HW);
    int k = chn >> 1;
    int b = chn & 1;          // 0 -> flow_h, 1 -> flow_w
    int is = k / 3, js = k - is * 3;
    int ys = y - is, xs = x - js;
    float val = 0.f;
    if (ys >= 0 && ys < HP && xs >= 0 && xs < HP) {
        int i = ys * HP + xs;
        unsigned long long key = best[(size_t)n * NP + i];
        int idx = (int)(~(unsigned int)key);
        int yr = idx / HP, xr = idx - yr * HP;
        val = b ? (float)(xr - xs) : (float)(yr - ys);
    }
    out[t] = val;
}

// ---------------- Launch ----------------
extern "C" void kernel_launch(void* const* d_in, const int* in_sizes, int n_in,
                              void* d_out, int out_size, void* d_ws, size_t ws_size,
                              hipStream_t stream) {
    (void)in_sizes; (void)n_in; (void)out_size; (void)ws_size;
    const float* f1 = (const float*)d_in[0];
    const float* f2 = (const float*)d_in[1];

    float2* fiP = (float2*)d_ws;                            // 2*96*32*96 float2 = 4.7 MB
    float2* frP = fiP + (size_t)NITEM * H * 32 * W;         // 4.7 MB
    float*  ssn = (float*)(frP + (size_t)NITEM * H * 32 * W);
    float*  invn = ssn + (size_t)NITEM * HW;
    unsigned long long* best =
        (unsigned long long*)((((uintptr_t)(invn + (size_t)NITEM * NP)) + 63) & ~(uintptr_t)63);
    unsigned int* tick = (unsigned int*)(best + (size_t)NITEM * NP);  // 2 pools, 64B apart
    // total ~9.7 MB of workspace

    normalize_kernel<<<(2 * NITEM * HW + 255) / 256, 256, 0, stream>>>(f1, f2, fiP, frP, ssn);
    refnorm_kernel<<<(NITEM * NP + 255) / 256, 256, 0, stream>>>(ssn, invn);
    hipMemsetAsync(best, 0, (size_t)NITEM * NP * sizeof(unsigned long long) + 512, stream);
    corr_fused_kernel<<<NBLOCKS, 256, 0, stream>>>(fiP, frP, invn, best, tick);
    expand_best_kernel<<<(NITEM * 18 * HW + 255) / 256, 256, 0, stream>>>(best, (float*)d_out);
}

// Round 7
// 626.602 us; speedup vs baseline: 20.6458x; 20.6458x over previous
//
#include <hip/hip_runtime.h>
#include <math.h>

// Problem constants (N=2, C=64, H=96, W=96, PATCH=3)
static constexpr int NITEM = 2;
static constexpr int C = 64;
static constexpr int W = 96;
static constexpr int H = 96;
static constexpr int HW = H * W;        // 9216
static constexpr int HP = 94;           // H - 3 + 1
static constexpr int NP = HP * HP;      // 8836

// Work units: per (n, dy) split the valid yi-range into PL-row pieces.
static constexpr int PL = 8;
static constexpr int UNITS_PER_N = 1188;
static constexpr int NBLOCKS = 1024;    // 4 blocks/CU x 256 CUs (VGPR=128, LDS 27KB)

// Order-preserving fp32 -> uint32 (v1 > v2  <=>  key(v1) > key(v2))
__device__ __forceinline__ unsigned int fkey(float v) {
    unsigned int u = __float_as_uint(v);
    return (u & 0x80000000u) ? ~u : (u | 0x80000000u);
}

// ---------------- Kernel 1: normalize + per-row panel repack ----------------
// fiP/frP: per-row panel images [n][row][c2][x] float2 (linear 24576B/row -> DMA-able)
__global__ __launch_bounds__(256) void normalize_kernel(
    const float* __restrict__ f1, const float* __restrict__ f2,
    float2* __restrict__ fiP, float2* __restrict__ frP, float* __restrict__ ssn)
{
    int t = blockIdx.x * 256 + threadIdx.x;
    const int perTensor = NITEM * HW;
    if (t >= 2 * perTensor) return;
    int which = t / perTensor;
    int p = t - which * perTensor;
    int n = p / HW;
    int pix = p - n * HW;
    const float* src = (which ? f2 : f1) + (size_t)n * C * HW + pix;
    float s = 0.f;
    #pragma unroll
    for (int c = 0; c < C; c++) {
        float v = src[c * HW];
        s = fmaf(v, v, s);
    }
    float norm = sqrtf(s);
    float scale = 1.0f / fmaxf(norm, 1e-12f);
    int y = pix / W, x = pix - y * W;
    float2* base = (which ? frP : fiP) + ((size_t)n * H + y) * (32 * W) + x;
    #pragma unroll
    for (int c2 = 0; c2 < 32; c2++)
        base[c2 * W] = make_float2(src[(2 * c2) * HW] * scale,
                                   src[(2 * c2 + 1) * HW] * scale);
    if (which) ssn[p] = s * scale * scale;
}

// ---------------- Kernel 2: ref patch inverse norms ----------------
__global__ __launch_bounds__(256) void refnorm_kernel(
    const float* __restrict__ ssn, float* __restrict__ invn)
{
    int t = blockIdx.x * 256 + threadIdx.x;
    if (t >= NITEM * NP) return;
    int n = t / NP;
    int r = t - n * NP;
    int yr = r / HP, xr = r - yr * HP;
    const float* s = ssn + n * HW;
    float acc = 0.f;
    #pragma unroll
    for (int dy = 0; dy < 3; dy++)
        #pragma unroll
        for (int dx = 0; dx < 3; dx++)
            acc += s[(yr + dy) * W + (xr + dx)];
    invn[t] = 1.0f / (sqrtf(acc) + 1e-5f);
}

// ---- async half-K staging: A-half 12288 B + B-half 12288 B -> the 24576 B slot ----
// 24 chunks of 1024 B; wave wv stages chunks 6wv..6wv+5 (A first 12, then B 12).
__device__ __forceinline__ void stage_half(const char* aH, const char* bH,
                                           char* slot, int wv, int lane)
{
#if defined(__has_builtin) && __has_builtin(__builtin_amdgcn_global_load_lds)
    #pragma unroll
    for (int c = 0; c < 6; ++c) {
        const int off = (wv * 6 + c) << 10;
        const char* g = ((off < 12288) ? (aH + off) : (bH + (off - 12288))) + lane * 16;
        __builtin_amdgcn_global_load_lds(
            (const __attribute__((address_space(1))) unsigned int*)(const void*)g,
            (__attribute__((address_space(3))) unsigned int*)(void*)(slot + off),
            16, 0, 0);
    }
#else
    #pragma unroll
    for (int c = 0; c < 6; ++c) {
        const int off = ((wv * 6 + c) << 10) + lane * 16;
        const char* g = (off < 12288) ? (aH + off) : (bH + (off - 12288));
        *(float4*)(slot + off) = *(const float4*)g;
    }
#endif
}

// ---------------- Kernel 3: fused row-pair GEMM + register diagonal taps + argmax ----
// R5 body (proven 613 us, VGPR 128, no spill) with ONE change: the K-panels go
// through a single 24.6 KB half-K slot (16 c2 of A + 16 c2 of B), staged twice per
// step, instead of 49 KB full panels. LDS 27 KB + VGPR 128 -> 4 blocks/CU (16 waves)
// vs R5's 3. Same staged bytes per step; math/association bit-identical to R0-R5.
// NOTE: __launch_bounds__ stays (256,2) — (256,4) halves the VGPR budget to 64 and
// spills the ~110-float register state (R6: 48 GB scratch traffic, 13 ms).
__global__ __launch_bounds__(256, 2) void corr_fused_kernel(
    const float2* __restrict__ fiP, const float2* __restrict__ frP,
    const float* __restrict__ invn, unsigned long long* __restrict__ best,
    unsigned int* __restrict__ tick)
{
    __shared__ struct {
        float2 slab[2][16][96];     // 24576 B: [op A/B][kp][x], one K-half
        float  sh[3][2][100];       //  2400 B: halo rows for wave-boundary groups
        int    sp;
    } sm;                           // ~26.4 KB -> LDS allows 4+ blocks/CU

    const int t = threadIdx.x;
    const int tu = t >> 4, tv = t & 15;     // 16x16 grid of 6x6 fragments
    const int lane = t & 63;
    const int quad = tu & 3;                // row-subgroup within wave
    const int wv = t >> 6;
    const int u0 = 6 * tu, v0 = 6 * tv;
    const unsigned long long gmask = 0xFFFFull << (lane & 48);

    const int n = blockIdx.x & 1;           // 512 blocks per item, XCD-interleaved

    const float2* fiPn = fiP + (size_t)n * H * (32 * W);
    const float2* frPn = frP + (size_t)n * H * (32 * W);
    const float* inv = invn + (size_t)n * NP;
    unsigned long long* bn = best + (size_t)n * NP;

    float pA[6][6], pB[6][6];

    for (;;) {
        if (t == 0) sm.sp = (int)atomicAdd(&tick[n * 16], 1u);
        __syncthreads();
        const int uj = sm.sp;               // unit index within item
        if (uj >= UNITS_PER_N) break;

        // ---- decode unit -> (dy, ya, nb), center-out dy order ----
        int dy = 0, ya = 0, nb = 0;
        {
            int r = uj;
            for (int s = 0; s < 187; ++s) {
                int ady = (s + 1) >> 1;          // 0,1,1,2,2,...,93,93
                int nyi = 94 - ady;
                int q = (nyi + PL - 1) / PL;
                if (r < q) {
                    dy = (s & 1) ? -ady : ady;
                    ya = (dy < 0 ? -dy : 0) + r * PL;
                    nb = nyi - r * PL; if (nb > PL) nb = PL;
                    break;
                }
                r -= q;
            }
        }
        const int yb = ya + nb;             // finalize yi in [ya, yb); y runs ya..yb+1

        // prologue: stage half0 (kp 0-15) of first row-pair
        stage_half((const char*)(fiPn + (size_t)ya * (32 * W)),
                   (const char*)(frPn + (size_t)(ya + dy) * (32 * W)),
                   (char*)&sm.slab[0][0][0], wv, lane);

        for (int y = ya; y <= yb + 1; ++y) {
            const bool doFin = (y >= ya + 2);
            const bool doA = (y > ya);
            const int yi = y - 2;
            const int yr = yi + dy;
            const char* rowA = (const char*)(fiPn + (size_t)y * (32 * W));
            const char* rowB = (const char*)(frPn + (size_t)(y + dy) * (32 * W));

            asm volatile("s_waitcnt vmcnt(0)" ::: "memory");
            __syncthreads();                // S1: half0 staged in all quarters

            float acc[6][6];
            #pragma unroll
            for (int i = 0; i < 6; ++i)
                #pragma unroll
                for (int jj = 0; jj < 6; ++jj) acc[i][jj] = 0.f;

            // ---- GEMM kp 0-15 from the slot ----
            #pragma unroll 2
            for (int kp = 0; kp < 16; ++kp) {
                const float4* ap = (const float4*)&sm.slab[0][kp][u0];
                const float4* bp = (const float4*)&sm.slab[1][kp][v0];
                float4 a01 = ap[0], a23 = ap[1], a45 = ap[2];
                float4 b01 = bp[0], b23 = bp[1], b45 = bp[2];
                float ae[6] = {a01.x, a01.z, a23.x, a23.z, a45.x, a45.z};
                float ao[6] = {a01.y, a01.w, a23.y, a23.w, a45.y, a45.w};
                float be[6] = {b01.x, b01.z, b23.x, b23.z, b45.x, b45.z};
                float bo[6] = {b01.y, b01.w, b23.y, b23.w, b45.y, b45.w};
                #pragma unroll
                for (int i = 0; i < 6; ++i)
                    #pragma unroll
                    for (int jj = 0; jj < 6; ++jj) {
                        acc[i][jj] = fmaf(ae[i], be[jj], acc[i][jj]);  // even ch then
                        acc[i][jj] = fmaf(ao[i], bo[jj], acc[i][jj]);  // odd: asc-c chain
                    }
            }
            __syncthreads();                // S2: half0 reads done
            stage_half(rowA + 12288, rowB + 12288,     // half1 (kp 16-31)
                       (char*)&sm.slab[0][0][0], wv, lane);
            asm volatile("s_waitcnt vmcnt(0)" ::: "memory");
            __syncthreads();                // S3: half1 staged (exposed DMA window)

            // ---- GEMM kp 16-31 ----
            #pragma unroll 2
            for (int kp = 0; kp < 16; ++kp) {
                const float4* ap = (const float4*)&sm.slab[0][kp][u0];
                const float4* bp = (const float4*)&sm.slab[1][kp][v0];
                float4 a01 = ap[0], a23 = ap[1], a45 = ap[2];
                float4 b01 = bp[0], b23 = bp[1], b45 = bp[2];
                float ae[6] = {a01.x, a01.z, a23.x, a23.z, a45.x, a45.z};
                float ao[6] = {a01.y, a01.w, a23.y, a23.w, a45.y, a45.w};
                float be[6] = {b01.x, b01.z, b23.x, b23.z, b45.x, b45.z};
                float bo[6] = {b01.y, b01.w, b23.y, b23.w, b45.y, b45.w};
                #pragma unroll
                for (int i = 0; i < 6; ++i)
                    #pragma unroll
                    for (int jj = 0; jj < 6; ++jj) {
                        acc[i][jj] = fmaf(ae[i], be[jj], acc[i][jj]);
                        acc[i][jj] = fmaf(ao[i], bo[jj], acc[i][jj]);
                    }
            }

            // publish halo rows 0,1 for wave-boundary consumers (tu in {3,7,11})
            if (quad == 0 && tu >= 4) {
                const int g = (tu >> 2) - 1;
                #pragma unroll
                for (int jj = 0; jj < 6; ++jj) {
                    sm.sh[g][0][v0 + jj] = acc[0][jj];
                    sm.sh[g][1][v0 + jj] = acc[1][jj];
                }
            }
            __syncthreads();                // S4: half1 reads done + halo visible

            // issue next row-pair's half0 DMA; latency hides under taps/finalize
            if (y < yb + 1)
                stage_half((const char*)(fiPn + (size_t)(y + 1) * (32 * W)),
                           (const char*)(frPn + (size_t)(y + 1 + dy) * (32 * W)),
                           (char*)&sm.slab[0][0][0], wv, lane);

            // ---- neighbor exchange (uniform shfls; select after) ----
            float c6[6], c7[6];
            #pragma unroll
            for (int i = 0; i < 6; ++i) {
                c6[i] = __shfl_down(acc[i][0], 1);   // col u0+i, v0+6
                c7[i] = __shfl_down(acc[i][1], 1);   // col u0+i, v0+7
            }
            float e6[8], e7[8];
            #pragma unroll
            for (int jj = 0; jj < 6; ++jj) {
                e6[jj] = __shfl_down(acc[0][jj], 16);  // row u0+6
                e7[jj] = __shfl_down(acc[1][jj], 16);  // row u0+7
            }
            e6[6] = __shfl_down(acc[0][0], 17);
            e6[7] = __shfl_down(acc[0][1], 17);
            e7[6] = __shfl_down(acc[1][0], 17);
            e7[7] = __shfl_down(acc[1][1], 17);
            if (quad == 3) {
                if (tu < 15) {
                    const int g = tu >> 2;
                    #pragma unroll
                    for (int jj = 0; jj < 8; ++jj) {
                        e6[jj] = sm.sh[g][0][v0 + jj];
                        e7[jj] = sm.sh[g][1][v0 + jj];
                    }
                } else {
                    #pragma unroll
                    for (int jj = 0; jj < 8; ++jj) { e6[jj] = 0.f; e7[jj] = 0.f; }
                }
            }

            float ivr[6];
            if (doFin) {
                const float* ivp = inv + (size_t)yr * HP;
                #pragma unroll
                for (int jj = 0; jj < 6; ++jj) {
                    int xr = v0 + jj;
                    ivr[jj] = ivp[xr > 93 ? 93 : xr];   // clamp; garbage masked later
                }
            }

            // ---- diagonal x-taps + y-rotation + finalize yi = y-2 ----
            #pragma unroll
            for (int i = 0; i < 6; ++i) {
                float bv = -INFINITY; int bxr = 0;
                #pragma unroll
                for (int jj = 0; jj < 6; ++jj) {
                    const int i1 = (i + 1 <= 5) ? i + 1 : 0;
                    const int j1 = (jj + 1 <= 5) ? jj + 1 : 0;
                    const int i2 = (i + 2 <= 5) ? i + 2 : 0;
                    const int j2 = (jj + 2 <= 5) ? jj + 2 : 0;
                    float E0 = acc[i][jj];
                    float E1 = (i + 1 <= 5)
                             ? ((jj + 1 <= 5) ? acc[i1][j1] : c6[i1])
                             : e6[jj + 1];
                    float E2 = (i + 2 <= 5)
                             ? ((jj + 2 <= 5) ? acc[i2][j2]
                                              : ((jj + 2 == 6) ? c6[i2] : c7[i2]))
                             : ((i + 2 == 6) ? e6[jj + 2] : e7[jj + 2]);
                    float bx = (E0 + E1) + E2;           // (g0+g1)+g2, as pass2
                    if (doFin) {
                        float v = (pA[i][jj] + bx) * ivr[jj];  // ((B0+B1)+B2)*inv
                        int xr = v0 + jj;
                        if (xr < HP && (u0 + i) < HP && v > bv) { bv = v; bxr = xr; }
                    }
                    if (doA) pA[i][jj] = pB[i][jj] + bx;
                    pB[i][jj] = bx;
                }
                if (doFin) {
                    float mx = bv;
                    #pragma unroll
                    for (int m = 1; m < 16; m <<= 1)
                        mx = fmaxf(mx, __shfl_xor(mx, m));   // 16-lane xr-group max
                    unsigned long long ball = __ballot(bv == mx) & gmask;
                    int srcl = __ffsll(ball) - 1;            // lowest lane = min xr
                    int wxr = __shfl(bxr, srcl);
                    if (tv == 0 && (u0 + i) < HP) {
                        unsigned long long key =
                            ((unsigned long long)fkey(mx) << 32)
                          | (unsigned int)(~(unsigned int)(yr * HP + wxr));
                        const size_t off = (size_t)yi * HP + (u0 + i);
                        if (key > bn[off]) atomicMax(&bn[off], key);  // monotone: stale-skip safe
                    }
                }
            }
        }
    }
}

// ---------------- Kernel 4: expand to 9 shifted copies, channel-interleaved ----------------
__global__ __launch_bounds__(256) void expand_best_kernel(
    const unsigned long long* __restrict__ best, float* __restrict__ out)
{
    int t = blockIdx.x * 256 + threadIdx.x;
    const int total = NITEM * 18 * HW;
    if (t >= total) return;
    int x = t % W;
    int y = (t / W) % H;
    int chn = (t / HW) % 18;
    int n = t / (18 * HW);
    int k = chn >> 1;
    int b = chn & 1;          // 0 -> flow_h, 1 -> flow_w
    int is = k / 3, js = k - is * 3;
    int ys = y - is, xs = x - js;
    float val = 0.f;
    if (ys >= 0 && ys < HP && xs >= 0 && xs < HP) {
        int i = ys * HP + xs;
        unsigned long long key = best[(size_t)n * NP + i];
        int idx = (int)(~(unsigned int)key);
        int yr = idx / HP, xr = idx - yr * HP;
        val = b ? (float)(xr - xs) : (float)(yr - ys);
    }
    out[t] = val;
}

// ---------------- Launch ----------------
extern "C" void kernel_launch(void* const* d_in, const int* in_sizes, int n_in,
                              void* d_out, int out_size, void* d_ws, size_t ws_size,
                              hipStream_t stream) {
    (void)in_sizes; (void)n_in; (void)out_size; (void)ws_size;
    const float* f1 = (const float*)d_in[0];
    const float* f2 = (const float*)d_in[1];

    float2* fiP = (float2*)d_ws;                            // 2*96*32*96 float2 = 4.7 MB
    float2* frP = fiP + (size_t)NITEM * H * 32 * W;         // 4.7 MB
    float*  ssn = (float*)(frP + (size_t)NITEM * H * 32 * W);
    float*  invn = ssn + (size_t)NITEM * HW;
    unsigned long long* best =
        (unsigned long long*)((((uintptr_t)(invn + (size_t)NITEM * NP)) + 63) & ~(uintptr_t)63);
    unsigned int* tick = (unsigned int*)(best + (size_t)NITEM * NP);  // 2 pools, 64B apart
    // total ~9.7 MB of workspace

    normalize_kernel<<<(2 * NITEM * HW + 255) / 256, 256, 0, stream>>>(f1, f2, fiP, frP, ssn);
    refnorm_kernel<<<(NITEM * NP + 255) / 256, 256, 0, stream>>>(ssn, invn);
    hipMemsetAsync(best, 0, (size_t)NITEM * NP * sizeof(unsigned long long) + 512, stream);
    corr_fused_kernel<<<NBLOCKS, 256, 0, stream>>>(fiP, frP, invn, best, tick);
    expand_best_kernel<<<(NITEM * 18 * HW + 255) / 256, 256, 0, stream>>>(best, (float*)d_out);
}

// Round 9
// 567.105 us; speedup vs baseline: 22.8118x; 1.1049x over previous
//
#include <hip/hip_runtime.h>
#include <math.h>

// Problem constants (N=2, C=64, H=96, W=96, PATCH=3)
static constexpr int NITEM = 2;
static constexpr int C = 64;
static constexpr int W = 96;
static constexpr int H = 96;
static constexpr int HW = H * W;        // 9216
static constexpr int HP = 94;           // H - 3 + 1
static constexpr int NP = HP * HP;      // 8836

// Work units: per (n, dy) split the valid yi-range into PL-row pieces.
static constexpr int PL = 8;
static constexpr int UNITS_PER_N = 1188;
static constexpr int NBLOCKS = 768;     // 3 blocks/CU x 256 CUs (proven R5 config)

typedef float f32x2 __attribute__((ext_vector_type(2)));

// Packed fp32 FMA with per-element fma semantics (bit-identical to scalar fmaf
// chains). Compiler lowers <2 x float> llvm.fma to v_pk_fma_f32 on gfx950.
#if defined(__has_builtin) && __has_builtin(__builtin_elementwise_fma)
#define VFMA(q, a, b) (q) = __builtin_elementwise_fma((a), (b), (q))
#else
#define VFMA(q, a, b) do { (q).x = fmaf((a).x, (b).x, (q).x); \
                           (q).y = fmaf((a).y, (b).y, (q).y); } while (0)
#endif

// Order-preserving fp32 -> uint32 (v1 > v2  <=>  key(v1) > key(v2))
__device__ __forceinline__ unsigned int fkey(float v) {
    unsigned int u = __float_as_uint(v);
    return (u & 0x80000000u) ? ~u : (u | 0x80000000u);
}

// ---------------- Kernel 1: normalize + per-row panel repack ----------------
// fiP/frP: per-row panel images [n][row][c][x] float, channel-major scalar
// (linear 24576B/row -> DMA-able; pixel-adjacent floats enable packed pairing).
__global__ __launch_bounds__(256) void normalize_kernel(
    const float* __restrict__ f1, const float* __restrict__ f2,
    float* __restrict__ fiP, float* __restrict__ frP, float* __restrict__ ssn)
{
    int t = blockIdx.x * 256 + threadIdx.x;
    const int perTensor = NITEM * HW;
    if (t >= 2 * perTensor) return;
    int which = t / perTensor;
    int p = t - which * perTensor;
    int n = p / HW;
    int pix = p - n * HW;
    const float* src = (which ? f2 : f1) + (size_t)n * C * HW + pix;
    float s = 0.f;
    #pragma unroll
    for (int c = 0; c < C; c++) {
        float v = src[c * HW];
        s = fmaf(v, v, s);
    }
    float norm = sqrtf(s);
    float scale = 1.0f / fmaxf(norm, 1e-12f);
    int y = pix / W, x = pix - y * W;
    float* base = (which ? frP : fiP) + ((size_t)n * H + y) * (C * W) + x;
    #pragma unroll
    for (int c = 0; c < C; c++)
        base[c * W] = src[c * HW] * scale;
    if (which) ssn[p] = s * scale * scale;
}

// ---------------- Kernel 2: ref patch inverse norms ----------------
__global__ __launch_bounds__(256) void refnorm_kernel(
    const float* __restrict__ ssn, float* __restrict__ invn)
{
    int t = blockIdx.x * 256 + threadIdx.x;
    if (t >= NITEM * NP) return;
    int n = t / NP;
    int r = t - n * NP;
    int yr = r / HP, xr = r - yr * HP;
    const float* s = ssn + n * HW;
    float acc = 0.f;
    #pragma unroll
    for (int dy = 0; dy < 3; dy++)
        #pragma unroll
        for (int dx = 0; dx < 3; dx++)
            acc += s[(yr + dy) * W + (xr + dx)];
    invn[t] = 1.0f / (sqrtf(acc) + 1e-5f);
}

// ---- async row staging: linear 24576B panel image -> LDS (per-wave quarter) ----
__device__ __forceinline__ void stage_row(const void* gsrc, void* ldst, int lane, int wv)
{
#if defined(__has_builtin) && __has_builtin(__builtin_amdgcn_global_load_lds)
    const char* g = (const char*)gsrc;
    char* l = (char*)ldst;
    #pragma unroll
    for (int c = 0; c < 6; ++c) {
        const int off = wv * 6144 + c * 1024;
        __builtin_amdgcn_global_load_lds(
            (const __attribute__((address_space(1))) unsigned int*)(const void*)(g + off + lane * 16),
            (__attribute__((address_space(3))) unsigned int*)(void*)(l + off),
            16, 0, 0);
    }
#else
    const char* g = (const char*)gsrc;
    char* l = (char*)ldst;
    #pragma unroll
    for (int c = 0; c < 6; ++c) {
        const int off = wv * 6144 + c * 1024 + lane * 16;
        *(float4*)(l + off) = *(const float4*)(g + off);
    }
#endif
}

// ---------------- Kernel 3: fused row-pair GEMM + register diagonal taps + argmax ----
// R5 body/schedule (proven 613 us) with the GEMM inner loop rewritten around packed
// fp32 FMAs: panels are scalar channel-major [64][96]; per channel each thread loads
// 3x f32x2 of A (u0..u0+5) and 3x f32x2 of B (v0..v0+5 pixel pairs) and issues 18
// packed FMAs, broadcasting each A scalar via .xx/.yy swizzles. Per-output
// association remains exactly "for c ascending: fma(a,b,acc)" -> bit-identical;
// GEMM issue slots drop ~2x (1152 pk_fma vs 2304 scalar fma + extraction movs).
__global__ __launch_bounds__(256, 2) void corr_fused_kernel(
    const float* __restrict__ fiP, const float* __restrict__ frP,
    const float* __restrict__ invn, unsigned long long* __restrict__ best,
    unsigned int* __restrict__ tick)
{
    __shared__ struct {
        float A[64][96];        // 24576 B: fi-row panel, channel-major
        float B[64][96];        // 24576 B: fr-row panel
        float sh[3][2][100];    //  2400 B: halo rows for wave-boundary groups
        int   sp;
    } sm;                       // ~51.6 KB -> 3 blocks/CU

    const int t = threadIdx.x;
    const int tu = t >> 4, tv = t & 15;     // 16x16 grid of 6x6 fragments
    const int lane = t & 63;
    const int quad = tu & 3;                // row-subgroup within wave
    const int wv = t >> 6;
    const int u0 = 6 * tu, v0 = 6 * tv;
    const unsigned long long gmask = 0xFFFFull << (lane & 48);

    const int n = blockIdx.x & 1;           // 384 blocks per item, XCD-interleaved

    const float* fiPn = fiP + (size_t)n * H * (C * W);
    const float* frPn = frP + (size_t)n * H * (C * W);
    const float* inv = invn + (size_t)n * NP;
    unsigned long long* bn = best + (size_t)n * NP;

    float pA[6][6], pB[6][6];

    for (;;) {
        if (t == 0) sm.sp = (int)atomicAdd(&tick[n * 16], 1u);
        __syncthreads();
        const int uj = sm.sp;               // unit index within item
        if (uj >= UNITS_PER_N) break;

        // ---- decode unit -> (dy, ya, nb), center-out dy order ----
        int dy = 0, ya = 0, nb = 0;
        {
            int r = uj;
            for (int s = 0; s < 187; ++s) {
                int ady = (s + 1) >> 1;          // 0,1,1,2,2,...,93,93
                int nyi = 94 - ady;
                int q = (nyi + PL - 1) / PL;
                if (r < q) {
                    dy = (s & 1) ? -ady : ady;
                    ya = (dy < 0 ? -dy : 0) + r * PL;
                    nb = nyi - r * PL; if (nb > PL) nb = PL;
                    break;
                }
                r -= q;
            }
        }
        const int yb = ya + nb;             // finalize yi in [ya, yb); y runs ya..yb+1

        // prologue: DMA rows (ya, ya+dy)
        stage_row(fiPn + (size_t)ya * (C * W), &sm.A[0][0], lane, wv);
        stage_row(frPn + (size_t)(ya + dy) * (C * W), &sm.B[0][0], lane, wv);
        asm volatile("s_waitcnt vmcnt(0)" ::: "memory");
        __syncthreads();

        for (int y = ya; y <= yb + 1; ++y) {
            const bool doLd = (y <= yb);
            const bool doFin = (y >= ya + 2);
            const bool doA = (y > ya);
            const int yi = y - 2;
            const int yr = yi + dy;

            // ---- GEMM: q[i][p] accumulates (acc[i][2p], acc[i][2p+1]) ----
            f32x2 q[6][3];
            #pragma unroll
            for (int i = 0; i < 6; ++i)
                #pragma unroll
                for (int p = 0; p < 3; ++p) q[i][p] = (f32x2)(0.f);

            #pragma unroll 4
            for (int c = 0; c < 64; ++c) {
                const f32x2* Ar = (const f32x2*)&sm.A[c][u0];   // 8B-aligned (u0 even)
                const f32x2* Br = (const f32x2*)&sm.B[c][v0];
                f32x2 a0 = Ar[0], a1 = Ar[1], a2 = Ar[2];       // u0..u0+5
                f32x2 b0 = Br[0], b1 = Br[1], b2 = Br[2];       // v0..v0+5 pixel pairs
                f32x2 s0 = a0.xx, s1 = a0.yy, s2 = a1.xx,
                      s3 = a1.yy, s4 = a2.xx, s5 = a2.yy;       // A scalar broadcasts
                VFMA(q[0][0], s0, b0); VFMA(q[0][1], s0, b1); VFMA(q[0][2], s0, b2);
                VFMA(q[1][0], s1, b0); VFMA(q[1][1], s1, b1); VFMA(q[1][2], s1, b2);
                VFMA(q[2][0], s2, b0); VFMA(q[2][1], s2, b1); VFMA(q[2][2], s2, b2);
                VFMA(q[3][0], s3, b0); VFMA(q[3][1], s3, b1); VFMA(q[3][2], s3, b2);
                VFMA(q[4][0], s4, b0); VFMA(q[4][1], s4, b1); VFMA(q[4][2], s4, b2);
                VFMA(q[5][0], s5, b0); VFMA(q[5][1], s5, b1); VFMA(q[5][2], s5, b2);
            }

            float acc[6][6];
            #pragma unroll
            for (int i = 0; i < 6; ++i)
                #pragma unroll
                for (int jj = 0; jj < 6; ++jj) acc[i][jj] = q[i][jj >> 1][jj & 1];

            // publish halo rows 0,1 for wave-boundary consumers (tu in {3,7,11})
            if (quad == 0 && tu >= 4) {
                const int g = (tu >> 2) - 1;
                #pragma unroll
                for (int jj = 0; jj < 6; ++jj) {
                    sm.sh[g][0][v0 + jj] = acc[0][jj];
                    sm.sh[g][1][v0 + jj] = acc[1][jj];
                }
            }
            __syncthreads();   // barrier1: GEMM panel reads done + halo visible

            // issue next-row DMA; latency hides under taps/finalize
            if (doLd) {
                stage_row(fiPn + (size_t)(y + 1) * (C * W), &sm.A[0][0], lane, wv);
                stage_row(frPn + (size_t)(y + 1 + dy) * (C * W), &sm.B[0][0], lane, wv);
            }

            // ---- neighbor exchange (uniform shfls; select after) ----
            float c6[6], c7[6];
            #pragma unroll
            for (int i = 0; i < 6; ++i) {
                c6[i] = __shfl_down(acc[i][0], 1);   // col u0+i, v0+6
                c7[i] = __shfl_down(acc[i][1], 1);   // col u0+i, v0+7
            }
            float e6[8], e7[8];
            #pragma unroll
            for (int jj = 0; jj < 6; ++jj) {
                e6[jj] = __shfl_down(acc[0][jj], 16);  // row u0+6
                e7[jj] = __shfl_down(acc[1][jj], 16);  // row u0+7
            }
            e6[6] = __shfl_down(acc[0][0], 17);
            e6[7] = __shfl_down(acc[0][1], 17);
            e7[6] = __shfl_down(acc[1][0], 17);
            e7[7] = __shfl_down(acc[1][1], 17);
            if (quad == 3) {
                if (tu < 15) {
                    const int g = tu >> 2;
                    #pragma unroll
                    for (int jj = 0; jj < 8; ++jj) {
                        e6[jj] = sm.sh[g][0][v0 + jj];
                        e7[jj] = sm.sh[g][1][v0 + jj];
                    }
                } else {
                    #pragma unroll
                    for (int jj = 0; jj < 8; ++jj) { e6[jj] = 0.f; e7[jj] = 0.f; }
                }
            }

            float ivr[6];
            if (doFin) {
                const float* ivp = inv + (size_t)yr * HP;
                #pragma unroll
                for (int jj = 0; jj < 6; ++jj) {
                    int xr = v0 + jj;
                    ivr[jj] = ivp[xr > 93 ? 93 : xr];   // clamp; garbage masked later
                }
            }

            // ---- diagonal x-taps + y-rotation + finalize yi = y-2 ----
            #pragma unroll
            for (int i = 0; i < 6; ++i) {
                float bv = -INFINITY; int bxr = 0;
                #pragma unroll
                for (int jj = 0; jj < 6; ++jj) {
                    const int i1 = (i + 1 <= 5) ? i + 1 : 0;
                    const int j1 = (jj + 1 <= 5) ? jj + 1 : 0;
                    const int i2 = (i + 2 <= 5) ? i + 2 : 0;
                    const int j2 = (jj + 2 <= 5) ? jj + 2 : 0;
                    float E0 = acc[i][jj];
                    float E1 = (i + 1 <= 5)
                             ? ((jj + 1 <= 5) ? acc[i1][j1] : c6[i1])
                             : e6[jj + 1];
                    float E2 = (i + 2 <= 5)
                             ? ((jj + 2 <= 5) ? acc[i2][j2]
                                              : ((jj + 2 == 6) ? c6[i2] : c7[i2]))
                             : ((i + 2 == 6) ? e6[jj + 2] : e7[jj + 2]);
                    float bx = (E0 + E1) + E2;           // (g0+g1)+g2, as pass2
                    if (doFin) {
                        float v = (pA[i][jj] + bx) * ivr[jj];  // ((B0+B1)+B2)*inv
                        int xr = v0 + jj;
                        if (xr < HP && (u0 + i) < HP && v > bv) { bv = v; bxr = xr; }
                    }
                    if (doA) pA[i][jj] = pB[i][jj] + bx;
                    pB[i][jj] = bx;
                }
                if (doFin) {
                    float mx = bv;
                    #pragma unroll
                    for (int m = 1; m < 16; m <<= 1)
                        mx = fmaxf(mx, __shfl_xor(mx, m));   // 16-lane xr-group max
                    unsigned long long ball = __ballot(bv == mx) & gmask;
                    int srcl = __ffsll(ball) - 1;            // lowest lane = min xr
                    int wxr = __shfl(bxr, srcl);
                    if (tv == 0 && (u0 + i) < HP) {
                        unsigned long long key =
                            ((unsigned long long)fkey(mx) << 32)
                          | (unsigned int)(~(unsigned int)(yr * HP + wxr));
                        const size_t off = (size_t)yi * HP + (u0 + i);
                        if (key > bn[off]) atomicMax(&bn[off], key);  // monotone: stale-skip safe
                    }
                }
            }

            if (doLd) asm volatile("s_waitcnt vmcnt(0)" ::: "memory");
            __syncthreads();   // barrier2: next panels staged in all quarters
        }
    }
}

// ---------------- Kernel 4: expand to 9 shifted copies, channel-interleaved ----------------
__global__ __launch_bounds__(256) void expand_best_kernel(
    const unsigned long long* __restrict__ best, float* __restrict__ out)
{
    int t = blockIdx.x * 256 + threadIdx.x;
    const int total = NITEM * 18 * HW;
    if (t >= total) return;
    int x = t % W;
    int y = (t / W) % H;
    int chn = (t / HW) % 18;
    int n = t / (18 * HW);
    int k = chn >> 1;
    int b = chn & 1;          // 0 -> flow_h, 1 -> flow_w
    int is = k / 3, js = k - is * 3;
    int ys = y - is, xs = x - js;
    float val = 0.f;
    if (ys >= 0 && ys < HP && xs >= 0 && xs < HP) {
        int i = ys * HP + xs;
        unsigned long long key = best[(size_t)n * NP + i];
        int idx = (int)(~(unsigned int)key);
        int yr = idx / HP, xr = idx - yr * HP;
        val = b ? (float)(xr - xs) : (float)(yr - ys);
    }
    out[t] = val;
}

// ---------------- Launch ----------------
extern "C" void kernel_launch(void* const* d_in, const int* in_sizes, int n_in,
                              void* d_out, int out_size, void* d_ws, size_t ws_size,
                              hipStream_t stream) {
    (void)in_sizes; (void)n_in; (void)out_size; (void)ws_size;
    const float* f1 = (const float*)d_in[0];
    const float* f2 = (const float*)d_in[1];

    float* fiP = (float*)d_ws;                              // 2*96*64*96 float = 4.7 MB
    float* frP = fiP + (size_t)NITEM * H * C * W;           // 4.7 MB
    float* ssn = frP + (size_t)NITEM * H * C * W;
    float* invn = ssn + (size_t)NITEM * HW;
    unsigned long long* best =
        (unsigned long long*)((((uintptr_t)(invn + (size_t)NITEM * NP)) + 63) & ~(uintptr_t)63);
    unsigned int* tick = (unsigned int*)(best + (size_t)NITEM * NP);  // 2 pools, 64B apart
    // total ~9.7 MB of workspace

    normalize_kernel<<<(2 * NITEM * HW + 255) / 256, 256, 0, stream>>>(f1, f2, fiP, frP, ssn);
    refnorm_kernel<<<(NITEM * NP + 255) / 256, 256, 0, stream>>>(ssn, invn);
    hipMemsetAsync(best, 0, (size_t)NITEM * NP * sizeof(unsigned long long) + 512, stream);
    corr_fused_kernel<<<NBLOCKS, 256, 0, stream>>>(fiP, frP, invn, best, tick);
    expand_best_kernel<<<(NITEM * 18 * HW + 255) / 256, 256, 0, stream>>>(best, (float*)d_out);
}